// Round 9
// baseline (76.426 us; speedup 1.0000x reference)
//
#include <hip/hip_runtime.h>
#include <hip/hip_bf16.h>
#include <hip/hip_fp16.h>
#include <math.h>

// ---------------------------------------------------------------------------
// HighFreqSuppressionLoss, real-packed rows + Hermitian-halved columns.
// gray = (0.299R+0.587G+0.114B+1)/2; F = fft2(gray);
// loss = mean_b | mean_M log10(|F_gen|^2+eps) - mean_M log10(|F_tgt|^2+eps) |
// Mask excludes (kx,ky) iff lowband(kx)&&lowband(ky); lowband: k<64||k>=448.
//
// Stage 1 (register-pipelined, high occupancy): pack rows (2p,2p+1) as
//   z = a+ib, one 512-pt FFT/pair; 4 pairs/wave. Iteration n: gray(cur)->LDS
//   (frees the 48 prefetch VGPRs), issue pair n+1's 12 float4 loads (pinned
//   above the FFT by sched_barrier), FFT from the 4.6KB exchange buffer.
//   Only ~19KB LDS/block -> 16 waves/CU: fences and load waits are hidden by
//   co-resident waves instead of being serially exposed (R7's 24KB/wave DMA
//   design capped at ~6 waves/CU and idled the SIMDs).
//   Z stored fp16 in TRUE FREQUENCY ORDER: ws[img][pair][kx],
//   kx = 64j + 8(t&7) + (t>>3).
// Stage 2: 16 columns/block (64B-sector stripe reads, own+mirror), kx=0..256;
//   element weight base=(kx==0||kx==256)?1:2, minus [kx<=63]*[ky in S],
//   minus [1<=kx<=64]*[ky in S']; S <=> j==0||j==7,
//   S' <=> j==0 || (j==1&&t==0) || (j==7&&t!=0). (weights total 245760;
//   logic byte-identical to passing R4-R8 kernels)
// ---------------------------------------------------------------------------

__device__ double g_partials[64 * 17 * 4];                   // [img][blk][wave]
__device__ __align__(16) __half2 g_ws[(size_t)64 * 256 * 512];  // 32 MiB

__device__ __forceinline__ float2 cadd(float2 a, float2 b){ return make_float2(a.x+b.x, a.y+b.y); }
__device__ __forceinline__ float2 csub(float2 a, float2 b){ return make_float2(a.x-b.x, a.y-b.y); }
__device__ __forceinline__ float2 cmul(float2 a, float2 b){
  return make_float2(fmaf(a.x, b.x, -(a.y*b.y)), fmaf(a.x, b.y, a.y*b.x));
}
__device__ __forceinline__ float2 mul_mi(float2 a){ return make_float2(a.y, -a.x); } // *(-i)

__device__ __forceinline__ void fft8(float2 v[8]){
  const float S = 0.70710678118654752440f;
  float2 c0=cadd(v[0],v[4]), c1=cadd(v[1],v[5]), c2=cadd(v[2],v[6]), c3=cadd(v[3],v[7]);
  float2 d0=csub(v[0],v[4]);
  float2 t1=csub(v[1],v[5]);
  float2 d1=make_float2(S*(t1.x+t1.y), S*(t1.y-t1.x));   // *w8^1
  float2 d2=mul_mi(csub(v[2],v[6]));                     // *w8^2
  float2 t3=csub(v[3],v[7]);
  float2 d3=make_float2(S*(t3.y-t3.x), -S*(t3.x+t3.y));  // *w8^3
  float2 e0=cadd(c0,c2), e1=cadd(c1,c3), f0=csub(c0,c2), f1=mul_mi(csub(c1,c3));
  float2 g0=cadd(d0,d2), g1=cadd(d1,d3), h0=csub(d0,d2), h1=mul_mi(csub(d1,d3));
  v[0]=cadd(e0,e1); v[4]=csub(e0,e1);
  v[2]=cadd(f0,f1); v[6]=csub(f0,f1);
  v[1]=cadd(g0,g1); v[5]=csub(g0,g1);
  v[3]=cadd(h0,h1); v[7]=csub(h0,h1);
}

__device__ __forceinline__ void twiddle8(float2 v[8], float ang){
  float sn, cs;
  __sincosf(ang, &sn, &cs);
  float2 w = make_float2(cs, sn);
  float2 wp = w;
  v[1] = cmul(v[1], wp);
  #pragma unroll
  for (int m = 2; m < 8; ++m){ wp = cmul(wp, w); v[m] = cmul(v[m], wp); }
}

__device__ __forceinline__ int padi(int i){ return i + (i >> 3); }

// Wave-internal LDS fence (exchange is intra-wave; no block barrier needed).
__device__ __forceinline__ void lds_fence(){
  asm volatile("s_waitcnt lgkmcnt(0)" ::: "memory");
  __builtin_amdgcn_sched_barrier(0);
}

// 512-pt DIF FFT across one wave. Lane t holds x[t+64j] on entry.
// Exit: reg j of lane t = stored s = 8t+j, true freq 64j + 8(t&7) + (t>>3).
__device__ __forceinline__ void fft512(float2 v[8], float* re, float* im, int t){
  const float TW = -6.28318530717958647692f;
  fft8(v);
  twiddle8(v, TW * (float)t * (1.0f/512.0f));
  lds_fence();
  #pragma unroll
  for (int m = 0; m < 8; ++m){ int a = padi(m*64 + t); re[a] = v[m].x; im[a] = v[m].y; }
  lds_fence();
  const int q = t >> 3, n = t & 7;
  #pragma unroll
  for (int j = 0; j < 8; ++j){ int a = padi(q*64 + n + 8*j); v[j].x = re[a]; v[j].y = im[a]; }
  fft8(v);
  twiddle8(v, TW * (float)n * (1.0f/64.0f));
  lds_fence();
  #pragma unroll
  for (int m = 0; m < 8; ++m){ int a = padi(q*64 + m*8 + n); re[a] = v[m].x; im[a] = v[m].y; }
  lds_fence();
  #pragma unroll
  for (int j = 0; j < 8; ++j){ int a = padi(q*64 + n*8 + j); v[j].x = re[a]; v[j].y = im[a]; }
  fft8(v);
}

#define GRAY1(r,g,b) ((fmaf(0.299f,(r), fmaf(0.587f,(g), 0.114f*(b))) + 1.0f)*0.5f)

// Stage 1: register-pipelined packed row-pair FFTs.
// Block 256 = 4 waves; 4 pairs/wave. Grid = 64 * 16.
// Register layout per pair: buf[c*4+s] = channel c, seg s (256 floats/seg);
// segs 0,1 = row A, segs 2,3 = row B. Lane t holds floats 4t..4t+3 of a seg.
__global__ __launch_bounds__(256, 4)
void k_rowfft(const float* __restrict__ gen, const float* __restrict__ tgt){
  const int wg   = blockIdx.x;
  const int img  = wg >> 4;
  const int bl   = wg & 15;
  const int wave = threadIdx.x >> 6, t = threadIdx.x & 63;
  const int pr0  = bl*16 + wave*4;               // first of 4 pairs
  const float* src = (img < 32) ? gen : tgt;
  const float4* f4 = (const float4*)(src + (size_t)(img & 31) * 786432
                                         + (size_t)pr0 * 1024) + t;
  // pair n: +n*256   channel c: +c*65536   seg s: +s*64   (float4 units)

  __shared__ float ex_all[4][1184];              // per wave: re[0..576) im[576..1152)
  float* re = ex_all[wave];
  float* im = ex_all[wave] + 576;

  const int off = 8*(t & 7) + (t >> 3);

  float4 bufA[12], bufB[12];
  #pragma unroll
  for (int c = 0; c < 3; ++c)
    #pragma unroll
    for (int s = 0; s < 4; ++s) bufA[c*4+s] = f4[c*65536 + s*64];

  #pragma unroll
  for (int n = 0; n < 4; ++n){
    const float4* cur = (n & 1) ? bufB : bufA;
    float4*       nxt = (n & 1) ? bufA : bufB;

    // (1) gray(cur) -> LDS natural positions (consumes cur, frees 48 VGPRs)
    #pragma unroll
    for (int s = 0; s < 2; ++s){
      const int x = s*256 + 4*t;
      float4 r = cur[0+s], g = cur[4+s], b = cur[8+s];        // row A
      re[padi(x+0)] = GRAY1(r.x, g.x, b.x);
      re[padi(x+1)] = GRAY1(r.y, g.y, b.y);
      re[padi(x+2)] = GRAY1(r.z, g.z, b.z);
      re[padi(x+3)] = GRAY1(r.w, g.w, b.w);
      float4 r2 = cur[2+s], g2 = cur[6+s], b2 = cur[10+s];    // row B
      im[padi(x+0)] = GRAY1(r2.x, g2.x, b2.x);
      im[padi(x+1)] = GRAY1(r2.y, g2.y, b2.y);
      im[padi(x+2)] = GRAY1(r2.z, g2.z, b2.z);
      im[padi(x+3)] = GRAY1(r2.w, g2.w, b2.w);
    }

    // (2) issue pair n+1 loads now; sched_barrier pins them above the FFT
    if (n < 3){
      #pragma unroll
      for (int c = 0; c < 3; ++c)
        #pragma unroll
        for (int s = 0; s < 4; ++s)
          nxt[c*4+s] = f4[(n+1)*256 + c*65536 + s*64];
      __builtin_amdgcn_sched_barrier(0);
    }

    // (3) FFT from LDS (z = grayA + i*grayB)
    lds_fence();
    float2 v[8];
    #pragma unroll
    for (int j = 0; j < 8; ++j){
      const int a = padi(t + 64*j);
      v[j] = make_float2(re[a], im[a]);
    }
    fft512(v, re, im, t);

    // Store fp16, TRUE frequency order: reg j -> kx = 64j + off.
    __half2* dst = g_ws + ((size_t)img * 256 + (pr0 + n)) * 512;
    #pragma unroll
    for (int j = 0; j < 8; ++j) dst[64*j + off] = __floats2half2_rn(v[j].x, v[j].y);
  }
}

// Stage 2: column FFTs for kx = 0..256 + masked log10 reduction.
// Blocks g=0..15: 16 cols kx=16g..16g+15 (4 cols/wave serially).
// Block g=16: kx=256 only (wave 0, ci 0). Grid = 64 * 17.
// Stripe reads are 64B/row sector-aligned chunks (own and mirror).
__global__ __launch_bounds__(256)
void k_colfft(){
  const int wg   = blockIdx.x;
  const int img  = wg / 17;
  const int blk  = wg - img * 17;
  const int kx0  = blk * 16;
  const int tid  = threadIdx.x;
  const int wave = tid >> 6, t = tid & 63;
  const int ncols = (blk == 16) ? 1 : 16;

  // raw half2 tiles, pad 258: load-writes <=2-way, col reads broadcast-free
  __shared__ __half2 own[16 * 258], mir[16 * 258];
  __shared__ float re_all[4][576], im_all[4][576];
  float* re = re_all[wave];
  float* im = im_all[wave];

  const __half2* zb = g_ws + (size_t)img * 131072;  // 256 pairs * 512
  #pragma unroll
  for (int it = 0; it < 16; ++it){
    const int idx = it*256 + tid;                   // 0..4095
    const int p = idx >> 4, e = idx & 15;
    own[e*258 + p] = zb[p*512 + kx0 + e];
    mir[e*258 + p] = zb[p*512 + ((512 - (kx0 + e)) & 511)];
  }
  __syncthreads();

  double acc = 0.0;
  for (int ci = 0; ci < 4; ++ci){
    const int e = wave*4 + ci;
    if (e < ncols){
      const int kx = kx0 + e;
      const bool sub_own = (kx <= 63);              // lowband(kx), kx in 0..256
      const bool sub_mir = (kx >= 1) & (kx <= 64);  // lowband(512-kx)
      const float base = (kx == 0 || kx == 256) ? 1.0f : 2.0f;

      float2 v[8];
      const int u = t >> 1;
      const bool odd = (t & 1);
      #pragma unroll
      for (int j = 0; j < 8; ++j){
        const int p = u + 32*j;
        float2 A = __half22float2(own[e*258 + p]);
        float2 B = __half22float2(mir[e*258 + p]); B.y = -B.y;   // conj
        float2 Fe = make_float2((A.x + B.x)*0.5f, (A.y + B.y)*0.5f);
        float2 Fo = mul_mi(make_float2((A.x - B.x)*0.5f, (A.y - B.y)*0.5f));
        v[j] = odd ? Fo : Fe;
      }
      fft512(v, re, im, t);

      #pragma unroll
      for (int j = 0; j < 8; ++j){
        const bool inS  = (j == 0) | (j == 7);
        const bool inSp = (j == 0) | ((j == 1) & (t == 0)) | ((j == 7) & (t != 0));
        float wgt = base;
        if (sub_own & inS)  wgt -= 1.0f;
        if (sub_mir & inSp) wgt -= 1.0f;
        float m2 = fmaf(v[j].x, v[j].x, fmaf(v[j].y, v[j].y, 1e-10f));
        acc += (double)wgt * (double)log10f(m2);
      }
    }
  }
  #pragma unroll
  for (int off = 32; off; off >>= 1) acc += __shfl_down(acc, off);
  if (t == 0) g_partials[((size_t)img * 17 + blk) * 4 + wave] = acc;
}

// Final: psd per image, L1 over batch.
__global__ __launch_bounds__(256)
void k_finish(float* __restrict__ out){
  const int tid = threadIdx.x;
  const int img = tid >> 2, part = tid & 3;
  const double* p = g_partials + (size_t)img * 68 + part;
  double s = 0.0;
  for (int k = 0; k < 17; ++k) s += p[4*k];
  __shared__ double sm[256];
  sm[tid] = s;
  __syncthreads();
  if ((tid & 3) == 0){
    double tot = sm[tid] + sm[tid+1] + sm[tid+2] + sm[tid+3];
    sm[tid] = tot * (1.0 / 245760.0);          // psd[img]
  }
  __syncthreads();
  if (tid < 64){
    double dv = (tid < 32) ? fabs(sm[tid*4] - sm[(tid+32)*4]) : 0.0;
    #pragma unroll
    for (int off = 32; off; off >>= 1) dv += __shfl_down(dv, off);
    if (tid == 0) out[0] = (float)(dv * (1.0 / 32.0));
  }
}

extern "C" void kernel_launch(void* const* d_in, const int* in_sizes, int n_in,
                              void* d_out, int out_size, void* d_ws, size_t ws_size,
                              hipStream_t stream){
  (void)in_sizes; (void)n_in; (void)out_size; (void)d_ws; (void)ws_size;
  const float* gen = (const float*)d_in[0];
  const float* tgt = (const float*)d_in[1];
  float* out = (float*)d_out;

  k_rowfft<<<dim3(64 * 16), dim3(256), 0, stream>>>(gen, tgt);
  k_colfft<<<dim3(64 * 17), dim3(256), 0, stream>>>();
  k_finish<<<dim3(1), dim3(256), 0, stream>>>(out);
}